// Round 10
// baseline (160272.766 us; speedup 1.0000x reference)
//
// R10: f32-grid replication probe — reproduce numpy-f32 arithmetic exactly.
#include <hip/hip_runtime.h>
#include <math.h>

#define B 8
#define D 256
#define V 50257
#define VP 50304
#define BEAM 32
#define STEPS 16
#define MAXLEN 17
#define FNEG_INF (-3.4e38f)

// -------- init --------
__global__ void k_init(const int* __restrict__ initial_ids, const float* __restrict__ state,
                       float* __restrict__ cache, int* __restrict__ ids, float* __restrict__ scores) {
    int b = blockIdx.x, t = threadIdx.x;
    cache[b * D + t] = state[b * D + t];
    if (t == 0) { ids[b * MAXLEN] = initial_ids[b]; scores[b] = 0.f; }
}

// -------- x = tanh(seqdot(cache,U) + emb[last]) on the f32 grid --------
__global__ __launch_bounds__(256) void k_embed(const float* __restrict__ cache, const int* __restrict__ ids,
                                               const float* __restrict__ emb, const float* __restrict__ U,
                                               float* __restrict__ x, int step) {
    int rr = blockIdx.x, j = threadIdx.x;
    __shared__ float sc[D];
    sc[j] = cache[rr * D + j];
    __syncthreads();
    int last = ids[rr * MAXLEN + step];
    float acc = 0.f;
    for (int d = 0; d < D; ++d)
        acc = __fadd_rn(acc, __fmul_rn(sc[d], U[d * D + j]));   // sequential f32, no FMA
    float pre = __fadd_rn(acc, emb[(size_t)last * D + j]);
    x[rr * D + j] = (float)tanh((double)pre);                    // correctly-rounded f32 tanh
}

// -------- logits: sequential f32 mul+add over d (np.einsum semantics) --------
__global__ __launch_bounds__(256) void k_gemm(const float* __restrict__ x, const float* __restrict__ W,
                                              float* __restrict__ L, int rows) {
    int v = blockIdx.x * 256 + threadIdx.x;
    int r = blockIdx.y;
    if (v >= V) return;
    const float* xr = x + (size_t)r * D;
    float acc = 0.f;
    for (int d = 0; d < D; ++d)
        acc = __fadd_rn(acc, __fmul_rn(xr[d], W[(size_t)d * V + v]));
    L[(size_t)r * VP + v] = acc;
}

// -------- numpy pairwise_sum (float32) exact replica --------
__device__ float np_pairwise(const float* a, int n) {
    if (n < 8) {
        if (n <= 0) return 0.f;
        float r = a[0];
        for (int i = 1; i < n; ++i) r = __fadd_rn(r, a[i]);
        return r;
    }
    if (n <= 128) {
        float r0 = a[0], r1 = a[1], r2 = a[2], r3 = a[3];
        float r4 = a[4], r5 = a[5], r6 = a[6], r7 = a[7];
        int i;
        for (i = 8; i < n - (n % 8); i += 8) {
            r0 = __fadd_rn(r0, a[i + 0]); r1 = __fadd_rn(r1, a[i + 1]);
            r2 = __fadd_rn(r2, a[i + 2]); r3 = __fadd_rn(r3, a[i + 3]);
            r4 = __fadd_rn(r4, a[i + 4]); r5 = __fadd_rn(r5, a[i + 5]);
            r6 = __fadd_rn(r6, a[i + 6]); r7 = __fadd_rn(r7, a[i + 7]);
        }
        float res = __fadd_rn(__fadd_rn(__fadd_rn(r0, r1), __fadd_rn(r2, r3)),
                              __fadd_rn(__fadd_rn(r4, r5), __fadd_rn(r6, r7)));
        for (; i < n; ++i) res = __fadd_rn(res, a[i]);
        return res;
    }
    int n2 = n / 2;
    n2 -= n2 % 8;
    return __fadd_rn(np_pairwise(a, n2), np_pairwise(a + n2, n - n2));
}

// -------- per-row: m = max(L); E = f32(exp(f64(L-m))); lsf = f32(log(f64(pairwise(E)))) --------
__global__ __launch_bounds__(256) void k_stats(const float* __restrict__ L, float* __restrict__ E,
                                               float* __restrict__ mArr, float* __restrict__ lsfArr) {
    int rr = blockIdx.x, t = threadIdx.x;
    const float* Lr = L + (size_t)rr * VP;
    float* Er = E + (size_t)rr * VP;
    __shared__ float red[256];
    float mx = FNEG_INF;
    for (int v = t; v < V; v += 256) mx = fmaxf(mx, Lr[v]);
    red[t] = mx; __syncthreads();
    for (int o = 128; o > 0; o >>= 1) { if (t < o) red[t] = fmaxf(red[t], red[t + o]); __syncthreads(); }
    float m = red[0];
    for (int v = t; v < V; v += 256)
        Er[v] = (float)exp((double)__fsub_rn(Lr[v], m));
    __syncthreads();
    if (t == 0) {
        float s = np_pairwise(Er, V);
        mArr[rr] = m;
        lsfArr[rr] = (float)log((double)s);
    }
}

// -------- SERIAL per-row top-32 on val = f32(score + f32((L-m)-lsf)) --------
__global__ void k_rowtop(const float* __restrict__ L, const float* __restrict__ scores,
                         const float* __restrict__ mArr, const float* __restrict__ lsfArr,
                         float* __restrict__ candV, int* __restrict__ candI) {
    int rr = blockIdx.x;
    if (threadIdx.x != 0) return;
    const float* Lr = L + (size_t)rr * VP;
    float m = mArr[rr], lsf = lsfArr[rr], sc = scores[rr];
    float best[BEAM]; int bidx[BEAM];
    for (int j = 0; j < BEAM; ++j) { best[j] = FNEG_INF; bidx[j] = 0x7fffffff; }
    for (int v = 0; v < V; ++v) {
        float ts  = __fsub_rn(__fsub_rn(Lr[v], m), lsf);   // token_score, f32 grid
        float val = __fadd_rn(sc, ts);                      // all_scores,  f32 grid
        if (!(val > best[BEAM - 1])) continue;              // equal => later index loses
        int pos = BEAM - 1;
        while (pos > 0 && val > best[pos - 1]) --pos;
        for (int j = BEAM - 1; j > pos; --j) { best[j] = best[j - 1]; bidx[j] = bidx[j - 1]; }
        best[pos] = val; bidx[pos] = v;
    }
    for (int j = 0; j < BEAM; ++j) { candV[rr * BEAM + j] = best[j]; candI[rr * BEAM + j] = bidx[j]; }
}

// -------- SERIAL per-batch merge (values already on final grid); gathers --------
__global__ __launch_bounds__(256) void k_merge(const float* __restrict__ candV, const int* __restrict__ candI,
                                               float* __restrict__ scoresNxt,
                                               const int* __restrict__ idsCur, int* __restrict__ idsNxt,
                                               const float* __restrict__ x, float* __restrict__ cacheNxt,
                                               int beam0, int step) {
    int b = blockIdx.x, t = threadIdx.x;
    __shared__ int wbeam[BEAM];
    if (t == 0) {
        float best[BEAM]; int bbm[BEAM]; int btk[BEAM];
        for (int j = 0; j < BEAM; ++j) { best[j] = FNEG_INF; bbm[j] = 0; btk[j] = 0; }
        int n = beam0 * BEAM;
        for (int i = 0; i < n; ++i) {           // ascending gi = beam*V + tok
            int beam = i >> 5, slot = i & 31;
            int rr = b * beam0 + beam;
            float val = candV[rr * BEAM + slot];
            if (!(val > best[BEAM - 1])) continue;
            int pos = BEAM - 1;
            while (pos > 0 && val > best[pos - 1]) --pos;
            for (int j = BEAM - 1; j > pos; --j) { best[j] = best[j - 1]; bbm[j] = bbm[j - 1]; btk[j] = btk[j - 1]; }
            best[pos] = val; bbm[pos] = beam; btk[pos] = candI[rr * BEAM + slot];
        }
        for (int j = 0; j < BEAM; ++j) {
            wbeam[j] = bbm[j];
            scoresNxt[b * BEAM + j] = best[j];
            int src = b * beam0 + bbm[j];
            for (int u = 0; u <= step; ++u)
                idsNxt[(b * BEAM + j) * MAXLEN + u] = idsCur[src * MAXLEN + u];
            idsNxt[(b * BEAM + j) * MAXLEN + step + 1] = btk[j];
        }
    }
    __syncthreads();
    for (int j = 0; j < BEAM; ++j) {
        int src = b * beam0 + wbeam[j];
        cacheNxt[(size_t)(b * BEAM + j) * D + t] = x[(size_t)src * D + t];
    }
}

// -------- output as float32 --------
__global__ void k_out(const int* __restrict__ ids, const float* __restrict__ scores, float* __restrict__ out) {
    int t = blockIdx.x * 256 + threadIdx.x;
    const int NI = B * BEAM * MAXLEN;
    if (t < NI) out[t] = (float)ids[t];
    else if (t < NI + B * BEAM) out[t] = scores[t - NI];
}

extern "C" void kernel_launch(void* const* d_in, const int* in_sizes, int n_in,
                              void* d_out, int out_size, void* d_ws, size_t ws_size,
                              hipStream_t stream) {
    const int* initial_ids = (const int*)d_in[0];
    const float* state = (const float*)d_in[1];
    const float* emb = (const float*)d_in[2];
    const float* W = (const float*)d_in[3];
    const float* U = (const float*)d_in[4];

    char* ws = (char*)d_ws;
    size_t off = 0;
    float* L = (float*)(ws + off);       off += (size_t)256 * VP * 4;
    float* E = (float*)(ws + off);       off += (size_t)256 * VP * 4;
    float* x = (float*)(ws + off);       off += 256 * D * 4;
    float* cacheA = (float*)(ws + off);  off += 256 * D * 4;
    float* cacheB = (float*)(ws + off);  off += 256 * D * 4;
    float* scoresA = (float*)(ws + off); off += 256 * 4;
    float* scoresB = (float*)(ws + off); off += 256 * 4;
    int* idsA = (int*)(ws + off);        off += 256 * MAXLEN * 4;
    int* idsB = (int*)(ws + off);        off += 256 * MAXLEN * 4;
    float* mArr = (float*)(ws + off);    off += 256 * 4;
    float* lsfArr = (float*)(ws + off);  off += 256 * 4;
    float* candV = (float*)(ws + off);   off += 256 * 32 * 4;
    int* candI = (int*)(ws + off);       off += 256 * 32 * 4;

    if (ws_size < off) return;

    k_init<<<B, 256, 0, stream>>>(initial_ids, state, cacheA, idsA, scoresA);

    float* cCur = cacheA; float* cNxt = cacheB;
    float* sCur = scoresA; float* sNxt = scoresB;
    int* iCur = idsA; int* iNxt = idsB;

    for (int step = 0; step < STEPS; ++step) {
        int beam0 = (step == 0) ? 1 : BEAM;
        int rows = B * beam0;

        k_embed<<<rows, 256, 0, stream>>>(cCur, iCur, emb, U, x, step);

        dim3 g((V + 255) / 256, rows);
        k_gemm<<<g, 256, 0, stream>>>(x, W, L, rows);

        k_stats<<<rows, 256, 0, stream>>>(L, E, mArr, lsfArr);
        k_rowtop<<<rows, 64, 0, stream>>>(L, sCur, mArr, lsfArr, candV, candI);
        k_merge<<<B, 256, 0, stream>>>(candV, candI, sNxt, iCur, iNxt, x, cNxt, beam0, step);

        float* tf; int* ti;
        tf = cCur; cCur = cNxt; cNxt = tf;
        tf = sCur; sCur = sNxt; sNxt = tf;
        ti = iCur; iCur = iNxt; iNxt = ti;
    }

    k_out<<<(B * BEAM * MAXLEN + B * BEAM + 255) / 256, 256, 0, stream>>>(iCur, sCur, (float*)d_out);
}

// Round 11
// 49940.155 us; speedup vs baseline: 3.2093x; 3.2093x over previous
//
// R11: parallelized version of the PASSING R10 f32-grid kernel.
// Every f32 operation is bit-identical to R10; only scheduling changed.
#include <hip/hip_runtime.h>
#include <math.h>

#define B 8
#define D 256
#define V 50257
#define VP 50304
#define BEAM 32
#define STEPS 16
#define MAXLEN 17
#define FNEG_INF (-3.4e38f)
#define NG 1571           // ceil(V/32)
#define MAXLEAF 1024

// -------- init --------
__global__ void k_init(const int* __restrict__ initial_ids, const float* __restrict__ state,
                       float* __restrict__ cache, int* __restrict__ ids, float* __restrict__ scores) {
    int b = blockIdx.x, t = threadIdx.x;
    cache[b * D + t] = state[b * D + t];
    if (t == 0) { ids[b * MAXLEN] = initial_ids[b]; scores[b] = 0.f; }
}

// -------- x = tanh(seqdot(cache,U) + emb[last]) on the f32 grid --------
__global__ __launch_bounds__(256) void k_embed(const float* __restrict__ cache, const int* __restrict__ ids,
                                               const float* __restrict__ emb, const float* __restrict__ U,
                                               float* __restrict__ x, int step) {
    int rr = blockIdx.x, j = threadIdx.x;
    __shared__ float sc[D];
    sc[j] = cache[rr * D + j];
    __syncthreads();
    int last = ids[rr * MAXLEN + step];
    float acc = 0.f;
    for (int d = 0; d < D; ++d)
        acc = __fadd_rn(acc, __fmul_rn(sc[d], U[d * D + j]));   // sequential f32, no FMA
    float pre = __fadd_rn(acc, emb[(size_t)last * D + j]);
    x[rr * D + j] = (float)tanh((double)pre);
}

// -------- logits GEMM: 32 rows/block, thread-per-column, sequential d --------
__global__ __launch_bounds__(256) void k_gemm(const float* __restrict__ x, const float* __restrict__ W,
                                              float* __restrict__ L, int rows) {
    __shared__ float xs[32][256];
    int t = threadIdx.x;
    int v = blockIdx.x * 256 + t;
    int r0 = blockIdx.y * 32;
#pragma unroll
    for (int i = 0; i < 32; ++i) {
        int idx = i * 256 + t;
        int r = idx >> 8, d = idx & 255;
        xs[r][d] = (r0 + r < rows) ? x[(size_t)(r0 + r) * D + d] : 0.f;
    }
    __syncthreads();
    float acc[32];
#pragma unroll
    for (int r = 0; r < 32; ++r) acc[r] = 0.f;
    if (v < V) {
        for (int d = 0; d < D; ++d) {
            float w = W[(size_t)d * V + v];                      // coalesced
#pragma unroll
            for (int r = 0; r < 32; ++r)
                acc[r] = __fadd_rn(acc[r], __fmul_rn(xs[r][d], w));  // same per-(r,v) op order as R10
        }
#pragma unroll
        for (int r = 0; r < 32; ++r)
            if (r0 + r < rows) L[(size_t)(r0 + r) * VP + v] = acc[r];
    }
}

// -------- exact numpy-pairwise base-case leaf sum with inlined exp --------
__device__ __forceinline__ float Ev(const float* __restrict__ a, float m, int i) {
    return (float)exp((double)__fsub_rn(a[i], m));
}
__device__ float leaf_sum(const float* __restrict__ a, int n, float m) {
    if (n < 8) {
        if (n <= 0) return 0.f;
        float r = Ev(a, m, 0);
        for (int i = 1; i < n; ++i) r = __fadd_rn(r, Ev(a, m, i));
        return r;
    }
    float r0 = Ev(a,m,0), r1 = Ev(a,m,1), r2 = Ev(a,m,2), r3 = Ev(a,m,3);
    float r4 = Ev(a,m,4), r5 = Ev(a,m,5), r6 = Ev(a,m,6), r7 = Ev(a,m,7);
    int i;
    for (i = 8; i < n - (n % 8); i += 8) {
        r0 = __fadd_rn(r0, Ev(a,m,i+0)); r1 = __fadd_rn(r1, Ev(a,m,i+1));
        r2 = __fadd_rn(r2, Ev(a,m,i+2)); r3 = __fadd_rn(r3, Ev(a,m,i+3));
        r4 = __fadd_rn(r4, Ev(a,m,i+4)); r5 = __fadd_rn(r5, Ev(a,m,i+5));
        r6 = __fadd_rn(r6, Ev(a,m,i+6)); r7 = __fadd_rn(r7, Ev(a,m,i+7));
    }
    float res = __fadd_rn(__fadd_rn(__fadd_rn(r0, r1), __fadd_rn(r2, r3)),
                          __fadd_rn(__fadd_rn(r4, r5), __fadd_rn(r6, r7)));
    for (; i < n; ++i) res = __fadd_rn(res, Ev(a,m,i));
    return res;
}

// -------- stats: parallel max + parallel-leaf exact pairwise + serial tree combine --------
__global__ __launch_bounds__(256) void k_stats(const float* __restrict__ L,
                                               float* __restrict__ mArr, float* __restrict__ lsfArr) {
    int rr = blockIdx.x, t = threadIdx.x;
    const float* Lr = L + (size_t)rr * VP;
    __shared__ float red[256];
    float mx = FNEG_INF;
    for (int v = t; v < V; v += 256) mx = fmaxf(mx, Lr[v]);
    red[t] = mx; __syncthreads();
    for (int o = 128; o > 0; o >>= 1) { if (t < o) red[t] = fmaxf(red[t], red[t + o]); __syncthreads(); }
    float m = red[0];

    __shared__ int leafOff[MAXLEAF]; __shared__ int leafN[MAXLEAF]; __shared__ float leafSum[MAXLEAF];
    __shared__ int nlS;
    __shared__ int stA[64]; __shared__ int stB[64];
    if (t == 0) {                 // enumerate numpy pairwise recursion leaves, left-to-right
        int sp = 0, nl = 0;
        stA[sp] = 0; stB[sp] = V; sp = 1;
        while (sp) {
            --sp; int off = stA[sp], n = stB[sp];
            if (n > 128) {
                int n2 = (n / 2) - ((n / 2) % 8);
                stA[sp] = off + n2; stB[sp] = n - n2; ++sp;   // right
                stA[sp] = off;      stB[sp] = n2;     ++sp;   // left (popped first)
            } else { leafOff[nl] = off; leafN[nl] = n; ++nl; }
        }
        nlS = nl;
    }
    __syncthreads();
    int nl = nlS;
    for (int l = t; l < nl; l += 256)
        leafSum[l] = leaf_sum(Lr + leafOff[l], leafN[l], m);
    __syncthreads();
    if (t == 0) {                 // replay combine tree in exact recursion order
        int  cN[64]; signed char cPh[64]; float vals[64];
        int sp = 0, vp = 0, ctr = 0;
        cN[sp] = V; cPh[sp] = 0; sp = 1;
        while (sp) {
            int idx = sp - 1;
            int n = cN[idx];
            if (n <= 128) { vals[vp++] = leafSum[ctr++]; --sp; continue; }
            int n2 = (n / 2) - ((n / 2) % 8);
            signed char ph = cPh[idx];
            if (ph == 0)      { cPh[idx] = 1; cN[sp] = n2;     cPh[sp] = 0; ++sp; }
            else if (ph == 1) { cPh[idx] = 2; cN[sp] = n - n2; cPh[sp] = 0; ++sp; }
            else { float bb = vals[--vp]; float aa = vals[--vp]; vals[vp++] = __fadd_rn(aa, bb); --sp; }
        }
        mArr[rr] = m;
        lsfArr[rr] = (float)log((double)vals[0]);
    }
}

// -------- parallel per-row top-32 on val grid (desc, ties -> lower idx) --------
__global__ __launch_bounds__(256) void k_rowtop(const float* __restrict__ L, const float* __restrict__ scores,
                                                const float* __restrict__ mArr, const float* __restrict__ lsfArr,
                                                float* __restrict__ candV, int* __restrict__ candI) {
    int rr = blockIdx.x, t = threadIdx.x;
    __shared__ float gval[NG]; __shared__ int gidx[NG]; __shared__ unsigned gmask[NG];
    __shared__ float rv[256]; __shared__ int ri[256];
    const float* Lr = L + (size_t)rr * VP;
    float m = mArr[rr], lsf = lsfArr[rr], sc = scores[rr];

    for (int g = t; g < NG; g += 256) {
        int c0 = g * 32;
        int lim = (V - c0) < 32 ? (V - c0) : 32;
        float bv = FNEG_INF; int bi = 0x7fffffff;
        for (int c = 0; c < lim; ++c) {
            int vtok = c0 + c;
            float val = __fadd_rn(sc, __fsub_rn(__fsub_rn(Lr[vtok], m), lsf));
            if (val > bv) { bv = val; bi = vtok; }              // ties keep lower idx
        }
        gval[g] = bv; gidx[g] = bi; gmask[g] = 0u;
    }
    __syncthreads();

    for (int it = 0; it < 32; ++it) {
        float bv = FNEG_INF; int bi = 0x7fffffff;
        for (int g = t; g < NG; g += 256) {
            float gv = gval[g]; int gi = gidx[g];
            if (gv > bv || (gv == bv && gi < bi)) { bv = gv; bi = gi; }
        }
        rv[t] = bv; ri[t] = bi; __syncthreads();
        for (int o = 128; o > 0; o >>= 1) {
            if (t < o) {
                if (rv[t + o] > rv[t] || (rv[t + o] == rv[t] && ri[t + o] < ri[t])) { rv[t] = rv[t + o]; ri[t] = ri[t + o]; }
            }
            __syncthreads();
        }
        int wcol = ri[0]; int wg = wcol >> 5;
        if (t == 0) {
            candV[rr * 32 + it] = rv[0];
            candI[rr * 32 + it] = wcol;
            gmask[wg] |= (1u << (wcol & 31));
        }
        __syncthreads();
        if (t < 32) {                                           // recompute winning group's max
            int col = wg * 32 + t;
            unsigned msk = gmask[wg];
            bool live = (col < V) && !((msk >> t) & 1u);
            float val = live ? __fadd_rn(sc, __fsub_rn(__fsub_rn(Lr[col], m), lsf)) : FNEG_INF;
            int ix = live ? col : 0x7fffffff;
            for (int o = 16; o > 0; o >>= 1) {
                float v2 = __shfl_down(val, o, 32);
                int i2 = __shfl_down(ix, o, 32);
                if (v2 > val || (v2 == val && i2 < ix)) { val = v2; ix = i2; }
            }
            if (t == 0) { gval[wg] = val; gidx[wg] = ix; }
        }
        __syncthreads();
    }
}

// -------- serial per-batch merge (tiny) + parallel cache gather --------
__global__ __launch_bounds__(256) void k_merge(const float* __restrict__ candV, const int* __restrict__ candI,
                                               float* __restrict__ scoresNxt,
                                               const int* __restrict__ idsCur, int* __restrict__ idsNxt,
                                               const float* __restrict__ x, float* __restrict__ cacheNxt,
                                               int beam0, int step) {
    int b = blockIdx.x, t = threadIdx.x;
    __shared__ int wbeam[BEAM];
    if (t == 0) {
        float best[BEAM]; int bbm[BEAM]; int btk[BEAM];
        for (int j = 0; j < BEAM; ++j) { best[j] = FNEG_INF; bbm[j] = 0; btk[j] = 0; }
        int n = beam0 * BEAM;
        for (int i = 0; i < n; ++i) {            // ascending gi = beam*V + tok
            int beam = i >> 5, slot = i & 31;
            int rr = b * beam0 + beam;
            float val = candV[rr * BEAM + slot];
            if (!(val > best[BEAM - 1])) continue;
            int pos = BEAM - 1;
            while (pos > 0 && val > best[pos - 1]) --pos;
            for (int j = BEAM - 1; j > pos; --j) { best[j] = best[j - 1]; bbm[j] = bbm[j - 1]; btk[j] = btk[j - 1]; }
            best[pos] = val; bbm[pos] = beam; btk[pos] = candI[rr * BEAM + slot];
        }
        for (int j = 0; j < BEAM; ++j) {
            wbeam[j] = bbm[j];
            scoresNxt[b * BEAM + j] = best[j];
            int src = b * beam0 + bbm[j];
            for (int u = 0; u <= step; ++u)
                idsNxt[(b * BEAM + j) * MAXLEN + u] = idsCur[src * MAXLEN + u];
            idsNxt[(b * BEAM + j) * MAXLEN + step + 1] = btk[j];
        }
    }
    __syncthreads();
    for (int j = 0; j < BEAM; ++j) {
        int src = b * beam0 + wbeam[j];
        cacheNxt[(size_t)(b * BEAM + j) * D + t] = x[(size_t)src * D + t];
    }
}

// -------- output as float32 --------
__global__ void k_out(const int* __restrict__ ids, const float* __restrict__ scores, float* __restrict__ out) {
    int t = blockIdx.x * 256 + threadIdx.x;
    const int NI = B * BEAM * MAXLEN;
    if (t < NI) out[t] = (float)ids[t];
    else if (t < NI + B * BEAM) out[t] = scores[t - NI];
}

extern "C" void kernel_launch(void* const* d_in, const int* in_sizes, int n_in,
                              void* d_out, int out_size, void* d_ws, size_t ws_size,
                              hipStream_t stream) {
    const int* initial_ids = (const int*)d_in[0];
    const float* state = (const float*)d_in[1];
    const float* emb = (const float*)d_in[2];
    const float* W = (const float*)d_in[3];
    const float* U = (const float*)d_in[4];

    char* ws = (char*)d_ws;
    size_t off = 0;
    float* L = (float*)(ws + off);       off += (size_t)256 * VP * 4;
    float* x = (float*)(ws + off);       off += 256 * D * 4;
    float* cacheA = (float*)(ws + off);  off += 256 * D * 4;
    float* cacheB = (float*)(ws + off);  off += 256 * D * 4;
    float* scoresA = (float*)(ws + off); off += 256 * 4;
    float* scoresB = (float*)(ws + off); off += 256 * 4;
    int* idsA = (int*)(ws + off);        off += 256 * MAXLEN * 4;
    int* idsB = (int*)(ws + off);        off += 256 * MAXLEN * 4;
    float* mArr = (float*)(ws + off);    off += 256 * 4;
    float* lsfArr = (float*)(ws + off);  off += 256 * 4;
    float* candV = (float*)(ws + off);   off += 256 * 32 * 4;
    int* candI = (int*)(ws + off);       off += 256 * 32 * 4;

    if (ws_size < off) return;

    k_init<<<B, 256, 0, stream>>>(initial_ids, state, cacheA, idsA, scoresA);

    float* cCur = cacheA; float* cNxt = cacheB;
    float* sCur = scoresA; float* sNxt = scoresB;
    int* iCur = idsA; int* iNxt = idsB;

    for (int step = 0; step < STEPS; ++step) {
        int beam0 = (step == 0) ? 1 : BEAM;
        int rows = B * beam0;

        k_embed<<<rows, 256, 0, stream>>>(cCur, iCur, emb, U, x, step);

        dim3 g((V + 255) / 256, (rows + 31) / 32);
        k_gemm<<<g, 256, 0, stream>>>(x, W, L, rows);

        k_stats<<<rows, 256, 0, stream>>>(L, mArr, lsfArr);
        k_rowtop<<<rows, 256, 0, stream>>>(L, sCur, mArr, lsfArr, candV, candI);
        k_merge<<<B, 256, 0, stream>>>(candV, candI, sNxt, iCur, iNxt, x, cNxt, beam0, step);

        float* tf; int* ti;
        tf = cCur; cCur = cNxt; cNxt = tf;
        tf = sCur; sCur = sNxt; sNxt = tf;
        ti = iCur; iCur = iNxt; iNxt = ti;
    }

    k_out<<<(B * BEAM * MAXLEN + B * BEAM + 255) / 256, 256, 0, stream>>>(iCur, sCur, (float*)d_out);
}

// Round 12
// 10048.552 us; speedup vs baseline: 15.9498x; 4.9699x over previous
//
// R12: k_stats rebuilt — precomputed pairwise schedule (k_sched, once/launch),
// float4 max pass, parallel leaf sums, level-parallel LDS combine.
// All f32 ops bit-identical to the PASSING R10/R11 grid.
#include <hip/hip_runtime.h>
#include <math.h>

#define B 8
#define D 256
#define V 50257
#define VP 50304
#define BEAM 32
#define STEPS 16
#define MAXLEN 17
#define FNEG_INF (-3.4e38f)
#define NG 1571           // ceil(V/32)
#define NLCAP 1024        // leaf slot capacity
#define SLOTCAP 2048      // leaves 0..1023, internal 1024+

// -------- init --------
__global__ void k_init(const int* __restrict__ initial_ids, const float* __restrict__ state,
                       float* __restrict__ cache, int* __restrict__ ids, float* __restrict__ scores) {
    int b = blockIdx.x, t = threadIdx.x;
    cache[b * D + t] = state[b * D + t];
    if (t == 0) { ids[b * MAXLEN] = initial_ids[b]; scores[b] = 0.f; }
}

// -------- schedule builder: numpy pairwise recursion tree for n=V (once/launch) --------
// sch layout (ints): [0]=nl [1]=nops [2]=nlev [3]=rootSlot
// [4..39]=lvlStart[0..35]  [40+]=leafOff[1024]  [1064+]=leafN[1024]
// [2088+]=sA[1024] [3112+]=sB[1024] [4136+]=sD[1024]
__global__ void k_sched(int* __restrict__ sch) {
    __shared__ int lOff[NLCAP], lN[NLCAP];
    __shared__ int oA[NLCAP], oB[NLCAP], oD[NLCAP], oL[NLCAP];
    __shared__ int sOff[64], sN[64], sPh[64];
    __shared__ int vSlot[64], vLev[64];
    __shared__ int meta[4];
    __shared__ int lvlStart[36];
    __shared__ int sA[NLCAP], sB[NLCAP], sD[NLCAP];
    int t = threadIdx.x;
    if (t == 0) {
        int sp = 0, vp = 0, nl = 0, nops = 0;
        sOff[0] = 0; sN[0] = V; sPh[0] = 0; sp = 1;
        while (sp) {
            int i = sp - 1;
            int n = sN[i];
            if (n <= 128) {                       // leaf (matches np_pairwise base case)
                lOff[nl] = sOff[i]; lN[nl] = n;
                vSlot[vp] = nl; vLev[vp] = 0; ++vp; ++nl; --sp; continue;
            }
            int n2 = (n / 2) - ((n / 2) % 8);
            int ph = sPh[i];
            if (ph == 0)      { sPh[i] = 1; sOff[sp] = sOff[i];      sN[sp] = n2;     sPh[sp] = 0; ++sp; }
            else if (ph == 1) { sPh[i] = 2; sOff[sp] = sOff[i] + n2; sN[sp] = n - n2; sPh[sp] = 0; ++sp; }
            else {
                int bI = --vp; int aI = --vp;     // a = left child, b = right child
                int lev = (vLev[aI] > vLev[bI] ? vLev[aI] : vLev[bI]) + 1;
                oA[nops] = vSlot[aI]; oB[nops] = vSlot[bI]; oD[nops] = NLCAP + nops; oL[nops] = lev;
                vSlot[vp] = NLCAP + nops; vLev[vp] = lev; ++vp; ++nops; --sp;
            }
        }
        meta[0] = nl; meta[1] = nops; meta[3] = vSlot[0];
        int maxl = 0;
        for (int k = 0; k < nops; ++k) if (oL[k] > maxl) maxl = oL[k];
        meta[2] = maxl;
        // counting sort ops by level
        int cnt[34];
        for (int k = 0; k <= maxl + 1; ++k) cnt[k] = 0;
        for (int k = 0; k < nops; ++k) cnt[oL[k]]++;
        int run = 0;
        lvlStart[0] = 0;
        for (int k = 1; k <= maxl; ++k) { lvlStart[k] = run; run += cnt[k]; cnt[k] = lvlStart[k]; }
        lvlStart[maxl + 1] = run;
        for (int k = 0; k < nops; ++k) { int p = cnt[oL[k]]++; sA[p] = oA[k]; sB[p] = oB[k]; sD[p] = oD[k]; }
    }
    __syncthreads();
    int nl = meta[0], nops = meta[1], nlev = meta[2];
    if (t == 0) { sch[0] = nl; sch[1] = nops; sch[2] = nlev; sch[3] = meta[3]; }
    for (int k = t; k <= nlev + 1; k += blockDim.x) sch[4 + k] = lvlStart[k];
    for (int k = t; k < nl; k += blockDim.x) { sch[40 + k] = lOff[k]; sch[1064 + k] = lN[k]; }
    for (int k = t; k < nops; k += blockDim.x) { sch[2088 + k] = sA[k]; sch[3112 + k] = sB[k]; sch[4136 + k] = sD[k]; }
}

// -------- x = tanh(seqdot(cache,U) + emb[last]) on the f32 grid --------
__global__ __launch_bounds__(256) void k_embed(const float* __restrict__ cache, const int* __restrict__ ids,
                                               const float* __restrict__ emb, const float* __restrict__ U,
                                               float* __restrict__ x, int step) {
    int rr = blockIdx.x, j = threadIdx.x;
    __shared__ float sc[D];
    sc[j] = cache[rr * D + j];
    __syncthreads();
    int last = ids[rr * MAXLEN + step];
    float acc = 0.f;
    for (int d = 0; d < D; ++d)
        acc = __fadd_rn(acc, __fmul_rn(sc[d], U[d * D + j]));   // sequential f32, no FMA
    float pre = __fadd_rn(acc, emb[(size_t)last * D + j]);
    x[rr * D + j] = (float)tanh((double)pre);
}

// -------- logits GEMM: 32 rows/block, thread-per-column, sequential d --------
__global__ __launch_bounds__(256) void k_gemm(const float* __restrict__ x, const float* __restrict__ W,
                                              float* __restrict__ L, int rows) {
    __shared__ float xs[32][256];
    int t = threadIdx.x;
    int v = blockIdx.x * 256 + t;
    int r0 = blockIdx.y * 32;
#pragma unroll
    for (int i = 0; i < 32; ++i) {
        int idx = i * 256 + t;
        int r = idx >> 8, d = idx & 255;
        xs[r][d] = (r0 + r < rows) ? x[(size_t)(r0 + r) * D + d] : 0.f;
    }
    __syncthreads();
    float acc[32];
#pragma unroll
    for (int r = 0; r < 32; ++r) acc[r] = 0.f;
    if (v < V) {
        for (int d = 0; d < D; ++d) {
            float w = W[(size_t)d * V + v];
#pragma unroll
            for (int r = 0; r < 32; ++r)
                acc[r] = __fadd_rn(acc[r], __fmul_rn(xs[r][d], w));
        }
#pragma unroll
        for (int r = 0; r < 32; ++r)
            if (r0 + r < rows) L[(size_t)(r0 + r) * VP + v] = acc[r];
    }
}

// -------- exact numpy-pairwise base-case leaf sum with inlined exp --------
__device__ __forceinline__ float Ev(const float* __restrict__ a, float m, int i) {
    return (float)exp((double)__fsub_rn(a[i], m));
}
__device__ float leaf_sum(const float* __restrict__ a, int n, float m) {
    if (n < 8) {
        if (n <= 0) return 0.f;
        float r = Ev(a, m, 0);
        for (int i = 1; i < n; ++i) r = __fadd_rn(r, Ev(a, m, i));
        return r;
    }
    float r0 = Ev(a,m,0), r1 = Ev(a,m,1), r2 = Ev(a,m,2), r3 = Ev(a,m,3);
    float r4 = Ev(a,m,4), r5 = Ev(a,m,5), r6 = Ev(a,m,6), r7 = Ev(a,m,7);
    int i;
    for (i = 8; i < n - (n % 8); i += 8) {
        r0 = __fadd_rn(r0, Ev(a,m,i+0)); r1 = __fadd_rn(r1, Ev(a,m,i+1));
        r2 = __fadd_rn(r2, Ev(a,m,i+2)); r3 = __fadd_rn(r3, Ev(a,m,i+3));
        r4 = __fadd_rn(r4, Ev(a,m,i+4)); r5 = __fadd_rn(r5, Ev(a,m,i+5));
        r6 = __fadd_rn(r6, Ev(a,m,i+6)); r7 = __fadd_rn(r7, Ev(a,m,i+7));
    }
    float res = __fadd_rn(__fadd_rn(__fadd_rn(r0, r1), __fadd_rn(r2, r3)),
                          __fadd_rn(__fadd_rn(r4, r5), __fadd_rn(r6, r7)));
    for (; i < n; ++i) res = __fadd_rn(res, Ev(a,m,i));
    return res;
}

// -------- stats: f4 max + parallel leaf sums + level-parallel combine --------
__global__ __launch_bounds__(512) void k_stats(const float* __restrict__ L, const int* __restrict__ sch,
                                               float* __restrict__ mArr, float* __restrict__ lsfArr) {
    int rr = blockIdx.x, t = threadIdx.x;
    const float* Lr = L + (size_t)rr * VP;
    __shared__ float red[512];
    float mx = FNEG_INF;
    const float4* L4 = (const float4*)Lr;
    for (int i = t; i < V / 4; i += 512) {          // 12564 float4 = 50256 elems
        float4 p = L4[i];
        mx = fmaxf(mx, fmaxf(fmaxf(p.x, p.y), fmaxf(p.z, p.w)));
    }
    if (t == 0) mx = fmaxf(mx, Lr[V - 1]);          // element 50256
    red[t] = mx; __syncthreads();
    for (int o = 256; o > 0; o >>= 1) { if (t < o) red[t] = fmaxf(red[t], red[t + o]); __syncthreads(); }
    float m = red[0];

    int nl = sch[0], nlev = sch[2], root = sch[3];
    const int* leafOff = sch + 40; const int* leafN = sch + 1064;
    const int* sA = sch + 2088; const int* sB = sch + 3112; const int* sD = sch + 4136;
    const int* lvlStart = sch + 4;
    __shared__ float vals[SLOTCAP];
    for (int l = t; l < nl; l += 512)
        vals[l] = leaf_sum(Lr + leafOff[l], leafN[l], m);
    __syncthreads();
    for (int lev = 1; lev <= nlev; ++lev) {
        for (int i = lvlStart[lev] + t; i < lvlStart[lev + 1]; i += 512)
            vals[sD[i]] = __fadd_rn(vals[sA[i]], vals[sB[i]]);
        __syncthreads();
    }
    if (t == 0) { mArr[rr] = m; lsfArr[rr] = (float)log((double)vals[root]); }
}

// -------- parallel per-row top-32 on val grid (desc, ties -> lower idx) --------
__global__ __launch_bounds__(256) void k_rowtop(const float* __restrict__ L, const float* __restrict__ scores,
                                                const float* __restrict__ mArr, const float* __restrict__ lsfArr,
                                                float* __restrict__ candV, int* __restrict__ candI) {
    int rr = blockIdx.x, t = threadIdx.x;
    __shared__ float gval[NG]; __shared__ int gidx[NG]; __shared__ unsigned gmask[NG];
    __shared__ float rv[256]; __shared__ int ri[256];
    const float* Lr = L + (size_t)rr * VP;
    float m = mArr[rr], lsf = lsfArr[rr], sc = scores[rr];

    for (int g = t; g < NG; g += 256) {
        int c0 = g * 32;
        int lim = (V - c0) < 32 ? (V - c0) : 32;
        float bv = FNEG_INF; int bi = 0x7fffffff;
        for (int c = 0; c < lim; ++c) {
            int vtok = c0 + c;
            float val = __fadd_rn(sc, __fsub_rn(__fsub_rn(Lr[vtok], m), lsf));
            if (val > bv) { bv = val; bi = vtok; }
        }
        gval[g] = bv; gidx[g] = bi; gmask[g] = 0u;
    }
    __syncthreads();

    for (int it = 0; it < 32; ++it) {
        float bv = FNEG_INF; int bi = 0x7fffffff;
        for (int g = t; g < NG; g += 256) {
            float gv = gval[g]; int gi = gidx[g];
            if (gv > bv || (gv == bv && gi < bi)) { bv = gv; bi = gi; }
        }
        rv[t] = bv; ri[t] = bi; __syncthreads();
        for (int o = 128; o > 0; o >>= 1) {
            if (t < o) {
                if (rv[t + o] > rv[t] || (rv[t + o] == rv[t] && ri[t + o] < ri[t])) { rv[t] = rv[t + o]; ri[t] = ri[t + o]; }
            }
            __syncthreads();
        }
        int wcol = ri[0]; int wg = wcol >> 5;
        if (t == 0) {
            candV[rr * 32 + it] = rv[0];
            candI[rr * 32 + it] = wcol;
            gmask[wg] |= (1u << (wcol & 31));
        }
        __syncthreads();
        if (t < 32) {
            int col = wg * 32 + t;
            unsigned msk = gmask[wg];
            bool live = (col < V) && !((msk >> t) & 1u);
            float val = live ? __fadd_rn(sc, __fsub_rn(__fsub_rn(Lr[col], m), lsf)) : FNEG_INF;
            int ix = live ? col : 0x7fffffff;
            for (int o = 16; o > 0; o >>= 1) {
                float v2 = __shfl_down(val, o, 32);
                int i2 = __shfl_down(ix, o, 32);
                if (v2 > val || (v2 == val && i2 < ix)) { val = v2; ix = i2; }
            }
            if (t == 0) { gval[wg] = val; gidx[wg] = ix; }
        }
        __syncthreads();
    }
}

// -------- serial per-batch merge (tiny) + parallel cache gather --------
__global__ __launch_bounds__(256) void k_merge(const float* __restrict__ candV, const int* __restrict__ candI,
                                               float* __restrict__ scoresNxt,
                                               const int* __restrict__ idsCur, int* __restrict__ idsNxt,
                                               const float* __restrict__ x, float* __restrict__ cacheNxt,
                                               int beam0, int step) {
    int b = blockIdx.x, t = threadIdx.x;
    __shared__ int wbeam[BEAM];
    if (t == 0) {
        float best[BEAM]; int bbm[BEAM]; int btk[BEAM];
        for (int j = 0; j < BEAM; ++j) { best[j] = FNEG_INF; bbm[j] = 0; btk[j] = 0; }
        int n = beam0 * BEAM;
        for (int i = 0; i < n; ++i) {            // ascending gi = beam*V + tok
            int beam = i >> 5, slot = i & 31;
            int rr = b * beam0 + beam;
            float val = candV[rr * BEAM + slot];
            if (!(val > best[BEAM - 1])) continue;
            int pos = BEAM - 1;
            while (pos > 0 && val > best[pos - 1]) --pos;
            for (int j = BEAM - 1; j > pos; --j) { best[j] = best[j - 1]; bbm[j] = bbm[j - 1]; btk[j] = btk[j - 1]; }
            best[pos] = val; bbm[pos] = beam; btk[pos] = candI[rr * BEAM + slot];
        }
        for (int j = 0; j < BEAM; ++j) {
            wbeam[j] = bbm[j];
            scoresNxt[b * BEAM + j] = best[j];
            int src = b * beam0 + bbm[j];
            for (int u = 0; u <= step; ++u)
                idsNxt[(b * BEAM + j) * MAXLEN + u] = idsCur[src * MAXLEN + u];
            idsNxt[(b * BEAM + j) * MAXLEN + step + 1] = btk[j];
        }
    }
    __syncthreads();
    for (int j = 0; j < BEAM; ++j) {
        int src = b * beam0 + wbeam[j];
        cacheNxt[(size_t)(b * BEAM + j) * D + t] = x[(size_t)src * D + t];
    }
}

// -------- output as float32 --------
__global__ void k_out(const int* __restrict__ ids, const float* __restrict__ scores, float* __restrict__ out) {
    int t = blockIdx.x * 256 + threadIdx.x;
    const int NI = B * BEAM * MAXLEN;
    if (t < NI) out[t] = (float)ids[t];
    else if (t < NI + B * BEAM) out[t] = scores[t - NI];
}

extern "C" void kernel_launch(void* const* d_in, const int* in_sizes, int n_in,
                              void* d_out, int out_size, void* d_ws, size_t ws_size,
                              hipStream_t stream) {
    const int* initial_ids = (const int*)d_in[0];
    const float* state = (const float*)d_in[1];
    const float* emb = (const float*)d_in[2];
    const float* W = (const float*)d_in[3];
    const float* U = (const float*)d_in[4];

    char* ws = (char*)d_ws;
    size_t off = 0;
    float* L = (float*)(ws + off);       off += (size_t)256 * VP * 4;
    float* x = (float*)(ws + off);       off += 256 * D * 4;
    float* cacheA = (float*)(ws + off);  off += 256 * D * 4;
    float* cacheB = (float*)(ws + off);  off += 256 * D * 4;
    float* scoresA = (float*)(ws + off); off += 256 * 4;
    float* scoresB = (float*)(ws + off); off += 256 * 4;
    int* idsA = (int*)(ws + off);        off += 256 * MAXLEN * 4;
    int* idsB = (int*)(ws + off);        off += 256 * MAXLEN * 4;
    float* mArr = (float*)(ws + off);    off += 256 * 4;
    float* lsfArr = (float*)(ws + off);  off += 256 * 4;
    float* candV = (float*)(ws + off);   off += 256 * 32 * 4;
    int* candI = (int*)(ws + off);       off += 256 * 32 * 4;
    int* sch = (int*)(ws + off);         off += 5200 * 4;

    if (ws_size < off) return;

    k_sched<<<1, 256, 0, stream>>>(sch);
    k_init<<<B, 256, 0, stream>>>(initial_ids, state, cacheA, idsA, scoresA);

    float* cCur = cacheA; float* cNxt = cacheB;
    float* sCur = scoresA; float* sNxt = scoresB;
    int* iCur = idsA; int* iNxt = idsB;

    for (int step = 0; step < STEPS; ++step) {
        int beam0 = (step == 0) ? 1 : BEAM;
        int rows = B * beam0;

        k_embed<<<rows, 256, 0, stream>>>(cCur, iCur, emb, U, x, step);

        dim3 g((V + 255) / 256, (rows + 31) / 32);
        k_gemm<<<g, 256, 0, stream>>>(x, W, L, rows);

        k_stats<<<rows, 512, 0, stream>>>(L, sch, mArr, lsfArr);
        k_rowtop<<<rows, 256, 0, stream>>>(L, sCur, mArr, lsfArr, candV, candI);
        k_merge<<<B, 256, 0, stream>>>(candV, candI, sNxt, iCur, iNxt, x, cNxt, beam0, step);

        float* tf; int* ti;
        tf = cCur; cCur = cNxt; cNxt = tf;
        tf = sCur; sCur = sNxt; sNxt = tf;
        ti = iCur; iCur = iNxt; iNxt = ti;
    }

    k_out<<<(B * BEAM * MAXLEN + B * BEAM + 255) / 256, 256, 0, stream>>>(iCur, sCur, (float*)d_out);
}

// Round 14
// 7598.244 us; speedup vs baseline: 21.0934x; 1.3225x over previous
//
// R13 resubmit (R14): compile-time pairwise schedule (constexpr), LDS-free
// scalar-broadcast GEMM via x-transpose, fused stats+rowtop.
// All f32 ops bit-identical to R10-R12 grid.
#include <hip/hip_runtime.h>
#include <math.h>

#define B 8
#define D 256
#define V 50257
#define VP 50304
#define BEAM 32
#define STEPS 16
#define MAXLEN 17
#define FNEG_INF (-3.4e38f)
#define NG 1571           // ceil(V/32)
#define NLCAP 800
#define SLOTCAP 1600

// ===== compile-time replica of numpy pairwise_sum recursion tree for n=V =====
struct SchedT {
    int nl, nops, nlev, root;
    int lvlStart[36];
    int leafOff[NLCAP];
    int leafN[NLCAP];
    int sA[NLCAP];
    int sB[NLCAP];
    int sD[NLCAP];
};

constexpr SchedT build_sched() {
    SchedT s{};
    int sOff[64] = {}, sN[64] = {}, sPh[64] = {};
    int vSlot[64] = {}, vLev[64] = {};
    int oA[NLCAP] = {}, oB[NLCAP] = {}, oD[NLCAP] = {}, oL[NLCAP] = {};
    int sp = 0, vp = 0, nl = 0, nops = 0;
    sOff[0] = 0; sN[0] = V; sPh[0] = 0; sp = 1;
    while (sp) {
        int i = sp - 1;
        int n = sN[i];
        if (n <= 128) {                        // leaf (np_pairwise base case)
            s.leafOff[nl] = sOff[i]; s.leafN[nl] = n;
            vSlot[vp] = nl; vLev[vp] = 0; ++vp; ++nl; --sp; continue;
        }
        int n2 = (n / 2) - ((n / 2) % 8);
        int ph = sPh[i];
        if (ph == 0)      { sPh[i] = 1; sOff[sp] = sOff[i];      sN[sp] = n2;     sPh[sp] = 0; ++sp; }
        else if (ph == 1) { sPh[i] = 2; sOff[sp] = sOff[i] + n2; sN[sp] = n - n2; sPh[sp] = 0; ++sp; }
        else {
            int bI = --vp; int aI = --vp;      // a = left child, b = right child
            int lev = (vLev[aI] > vLev[bI] ? vLev[aI] : vLev[bI]) + 1;
            oA[nops] = vSlot[aI]; oB[nops] = vSlot[bI]; oD[nops] = NLCAP + nops; oL[nops] = lev;
            vSlot[vp] = NLCAP + nops; vLev[vp] = lev; ++vp; ++nops; --sp;
        }
    }
    s.nl = nl; s.nops = nops; s.root = vSlot[0];
    int maxl = 0;
    for (int k = 0; k < nops; ++k) if (oL[k] > maxl) maxl = oL[k];
    s.nlev = maxl;
    int cnt[36] = {};
    for (int k = 0; k < nops; ++k) cnt[oL[k]]++;
    int run = 0;
    s.lvlStart[0] = 0;
    for (int k = 1; k <= maxl; ++k) { s.lvlStart[k] = run; run += cnt[k]; cnt[k] = s.lvlStart[k]; }
    s.lvlStart[maxl + 1] = run;
    for (int k = 0; k < nops; ++k) { int p = cnt[oL[k]]++; s.sA[p] = oA[k]; s.sB[p] = oB[k]; s.sD[p] = oD[k]; }
    return s;
}

constexpr SchedT SCH = build_sched();
static_assert(SCH.nl <= NLCAP, "leaf overflow");
static_assert(SCH.nops <= NLCAP, "op overflow");
static_assert(SCH.nlev <= 34, "level overflow");
static_assert(SCH.root < SLOTCAP, "slot overflow");

// -------- init --------
__global__ void k_init(const int* __restrict__ initial_ids, const float* __restrict__ state,
                       float* __restrict__ cache, int* __restrict__ ids, float* __restrict__ scores) {
    int b = blockIdx.x, t = threadIdx.x;
    cache[b * D + t] = state[b * D + t];
    if (t == 0) { ids[b * MAXLEN] = initial_ids[b]; scores[b] = 0.f; }
}

// -------- x = tanh(seqdot(cache,U) + emb[last]) on the f32 grid --------
__global__ __launch_bounds__(256) void k_embed(const float* __restrict__ cache, const int* __restrict__ ids,
                                               const float* __restrict__ emb, const float* __restrict__ U,
                                               float* __restrict__ x, int step) {
    int rr = blockIdx.x, j = threadIdx.x;
    __shared__ float sc[D];
    sc[j] = cache[rr * D + j];
    __syncthreads();
    int last = ids[rr * MAXLEN + step];
    float acc = 0.f;
    for (int d = 0; d < D; ++d)
        acc = __fadd_rn(acc, __fmul_rn(sc[d], U[d * D + j]));   // sequential f32, no FMA
    float pre = __fadd_rn(acc, emb[(size_t)last * D + j]);
    x[rr * D + j] = (float)tanh((double)pre);
}

// -------- 256x256 transpose: xT[c][r] = x[r][c] --------
__global__ __launch_bounds__(256) void k_trans(const float* __restrict__ x, float* __restrict__ xT) {
    __shared__ float tile[32][33];
    int t = threadIdx.x;
    int tx = t & 31, ty = t >> 5;          // 32 x 8
    int bx = blockIdx.x * 32, by = blockIdx.y * 32;
#pragma unroll
    for (int i = 0; i < 4; ++i)
        tile[ty + i * 8][tx] = x[(size_t)(by + ty + i * 8) * D + bx + tx];
    __syncthreads();
#pragma unroll
    for (int i = 0; i < 4; ++i)
        xT[(size_t)(bx + ty + i * 8) * 256 + by + tx] = tile[tx][ty + i * 8];
}

// -------- logits GEMM: LDS-free; x values wave-uniform (scalar loads) --------
__global__ __launch_bounds__(256) void k_gemm(const float* __restrict__ xT, const float* __restrict__ W,
                                              float* __restrict__ L, int rows) {
    int t = threadIdx.x;
    int v = blockIdx.x * 256 + t;
    int r0 = blockIdx.y * 32;
    if (v >= V) return;
    float acc[32];
#pragma unroll
    for (int r = 0; r < 32; ++r) acc[r] = 0.f;
    for (int d = 0; d < D; ++d) {
        float w = W[(size_t)d * V + v];                  // coalesced vector load
        const float* xp = xT + d * 256 + r0;             // block-uniform -> s_load
#pragma unroll
        for (int r = 0; r < 32; ++r)
            acc[r] = __fadd_rn(acc[r], __fmul_rn(xp[r], w));   // same per-(r,v) order as R10-R12
    }
#pragma unroll
    for (int r = 0; r < 32; ++r)
        if (r0 + r < rows) L[(size_t)(r0 + r) * VP + v] = acc[r];
}

// -------- exact numpy-pairwise base-case leaf sum with inlined exp --------
__device__ __forceinline__ float Ev(const float* __restrict__ a, float m, int i) {
    return (float)exp((double)__fsub_rn(a[i], m));
}
__device__ float leaf_sum(const float* __restrict__ a, int n, float m) {
    if (n < 8) {
        if (n <= 0) return 0.f;
        float r = Ev(a, m, 0);
        for (int i = 1; i < n; ++i) r = __fadd_rn(r, Ev(a, m, i));
        return r;
    }
    float r0 = Ev(a,m,0), r1 = Ev(a,m,1), r2 = Ev(a,m,2), r3 = Ev(a,m,3);
    float r4 = Ev(a,m,4), r5 = Ev(a,m,5), r6 = Ev(a,m,6), r7 = Ev(a,m,7);
    int i;
    for (i = 8; i < n - (n % 8); i += 8) {
        r0 = __fadd_rn(r0, Ev(a,m,i+0)); r1 = __fadd_rn(r1, Ev(a,m,i+1));
        r2 = __fadd_rn(r2, Ev(a,m,i+2)); r3 = __fadd_rn(r3, Ev(a,m,i+3));
        r4 = __fadd_rn(r4, Ev(a,m,i+4)); r5 = __fadd_rn(r5, Ev(a,m,i+5));
        r6 = __fadd_rn(r6, Ev(a,m,i+6)); r7 = __fadd_rn(r7, Ev(a,m,i+7));
    }
    float res = __fadd_rn(__fadd_rn(__fadd_rn(r0, r1), __fadd_rn(r2, r3)),
                          __fadd_rn(__fadd_rn(r4, r5), __fadd_rn(r6, r7)));
    for (; i < n; ++i) res = __fadd_rn(res, Ev(a,m,i));
    return res;
}

// -------- fused: max + lsf + per-row top-32 --------
__global__ __launch_bounds__(512) void k_post(const float* __restrict__ L, const float* __restrict__ scores,
                                              float* __restrict__ candV, int* __restrict__ candI) {
    int rr = blockIdx.x, t = threadIdx.x;
    const float* Lr = L + (size_t)rr * VP;
    __shared__ float red[512];
    __shared__ int ri[512];
    __shared__ float vals[SLOTCAP];
    __shared__ float gval[NG]; __shared__ int gidx[NG]; __shared__ unsigned gmask[NG];

    // ---- max (order-independent) ----
    float mx = FNEG_INF;
    const float4* L4 = (const float4*)Lr;
    for (int i = t; i < V / 4; i += 512) {
        float4 p = L4[i];
        mx = fmaxf(mx, fmaxf(fmaxf(p.x, p.y), fmaxf(p.z, p.w)));
    }
    if (t == 0) mx = fmaxf(mx, Lr[V - 1]);
    red[t] = mx; __syncthreads();
    for (int o = 256; o > 0; o >>= 1) { if (t < o) red[t] = fmaxf(red[t], red[t + o]); __syncthreads(); }
    float m = red[0];

    // ---- lsf: parallel leaf sums + level-parallel exact combine ----
    for (int l = t; l < SCH.nl; l += 512)
        vals[l] = leaf_sum(Lr + SCH.leafOff[l], SCH.leafN[l], m);
    __syncthreads();
    for (int lev = 1; lev <= SCH.nlev; ++lev) {
        for (int i = SCH.lvlStart[lev] + t; i < SCH.lvlStart[lev + 1]; i += 512)
            vals[SCH.sD[i]] = __fadd_rn(vals[SCH.sA[i]], vals[SCH.sB[i]]);
        __syncthreads();
    }
    float lsf = (float)log((double)vals[SCH.root]);
    float sc = scores[rr];

    // ---- group maxima over 32-token groups ----
    for (int g = t; g < NG; g += 512) {
        int c0 = g * 32;
        int lim = (V - c0) < 32 ? (V - c0) : 32;
        float bv = FNEG_INF; int bi = 0x7fffffff;
        for (int c = 0; c < lim; ++c) {
            int vtok = c0 + c;
            float val = __fadd_rn(sc, __fsub_rn(__fsub_rn(Lr[vtok], m), lsf));
            if (val > bv) { bv = val; bi = vtok; }       // ties keep lower idx
        }
        gval[g] = bv; gidx[g] = bi; gmask[g] = 0u;
    }
    __syncthreads();

    // ---- 32 extract rounds ----
    for (int it = 0; it < 32; ++it) {
        float bv = FNEG_INF; int bi = 0x7fffffff;
        for (int g = t; g < NG; g += 512) {
            float gv = gval[g]; int gi = gidx[g];
            if (gv > bv || (gv == bv && gi < bi)) { bv = gv; bi = gi; }
        }
        red[t] = bv; ri[t] = bi; __syncthreads();
        for (int o = 256; o > 0; o >>= 1) {
            if (t < o) {
                if (red[t + o] > red[t] || (red[t + o] == red[t] && ri[t + o] < ri[t])) { red[t] = red[t + o]; ri[t] = ri[t + o]; }
            }
            __syncthreads();
        }
        int wcol = ri[0]; int wg = wcol >> 5;
        if (t == 0) {
            candV[rr * 32 + it] = red[0];
            candI[rr * 32 + it] = wcol;
            gmask[wg] |= (1u << (wcol & 31));
        }
        __syncthreads();
        if (t < 32) {                                    // rescan winning group
            int col = wg * 32 + t;
            unsigned msk = gmask[wg];
            bool live = (col < V) && !((msk >> t) & 1u);
            float val = live ? __fadd_rn(sc, __fsub_rn(__fsub_rn(Lr[col], m), lsf)) : FNEG_INF;
            int ix = live ? col : 0x7fffffff;
            for (int o = 16; o > 0; o >>= 1) {
                float v2 = __shfl_down(val, o, 32);
                int i2 = __shfl_down(ix, o, 32);
                if (v2 > val || (v2 == val && i2 < ix)) { val = v2; ix = i2; }
            }
            if (t == 0) { gval[wg] = val; gidx[wg] = ix; }
        }
        __syncthreads();
    }
}

// -------- serial per-batch merge (tiny) + parallel cache gather --------
__global__ __launch_bounds__(256) void k_merge(const float* __restrict__ candV, const int* __restrict__ candI,
                                               float* __restrict__ scoresNxt,
                                               const int* __restrict__ idsCur, int* __restrict__ idsNxt,
                                               const float* __restrict__ x, float* __restrict__ cacheNxt,
                                               int beam0, int step) {
    int b = blockIdx.x, t = threadIdx.x;
    __shared__ int wbeam[BEAM];
    if (t == 0) {
        float best[BEAM]; int bbm[BEAM]; int btk[BEAM];
        for (int j = 0; j < BEAM; ++j) { best[j] = FNEG_INF; bbm[j] = 0; btk[j] = 0; }
        int n = beam0 * BEAM;
        for (int i = 0; i < n; ++i) {            // ascending gi = beam*V + tok
            int beam = i >> 5, slot = i & 31;
            int rr = b * beam0 + beam;
            float val = candV[rr * BEAM + slot];
            if (!(val > best[BEAM - 1])) continue;
            int pos = BEAM - 1;
            while (pos > 0 && val > best[pos - 1]) --pos;
            for (int j = BEAM - 1; j > pos; --j) { best[j] = best[j - 1]; bbm[j] = bbm[j - 1]; btk[j] = btk[j - 1]; }
            best[pos] = val; bbm[pos] = beam; btk[pos] = candI[rr * BEAM + slot];
        }
        for (int j = 0; j < BEAM; ++j) {
            wbeam[j] = bbm[j];
            scoresNxt[b * BEAM + j] = best[j];
            int src = b * beam0 + bbm[j];
            for (int u = 0; u <= step; ++u)
                idsNxt[(b * BEAM + j) * MAXLEN + u] = idsCur[src * MAXLEN + u];
            idsNxt[(b * BEAM + j) * MAXLEN + step + 1] = btk[j];
        }
    }
    __syncthreads();
    for (int j = 0; j < BEAM; ++j) {
        int src = b * beam0 + wbeam[j];
        cacheNxt[(size_t)(b * BEAM + j) * D + t] = x[(size_t)src * D + t];
    }
}

// -------- output as float32 --------
__global__ void k_out(const int* __restrict__ ids, const float* __restrict__ scores, float* __restrict__ out) {
    int t = blockIdx.x * 256 + threadIdx.x;
    const int NI = B * BEAM * MAXLEN;
    if (t < NI) out[t] = (float)ids[t];
    else if (t < NI + B * BEAM) out[t] = scores[t - NI];
}

extern "C" void kernel_launch(void* const* d_in, const int* in_sizes, int n_in,
                              void* d_out, int out_size, void* d_ws, size_t ws_size,
                              hipStream_t stream) {
    const int* initial_ids = (const int*)d_in[0];
    const float* state = (const float*)d_in[1];
    const float* emb = (const float*)d_in[2];
    const float* W = (const float*)d_in[3];
    const float* U = (const float*)d_in[4];

    char* ws = (char*)d_ws;
    size_t off = 0;
    float* L = (float*)(ws + off);       off += (size_t)256 * VP * 4;
    float* x = (float*)(ws + off);       off += 256 * D * 4;
    float* xT = (float*)(ws + off);      off += 256 * D * 4;
    float* cacheA = (float*)(ws + off);  off += 256 * D * 4;
    float* cacheB = (float*)(ws + off);  off += 256 * D * 4;
    float* scoresA = (float*)(ws + off); off += 256 * 4;
    float* scoresB = (float*)(ws + off); off += 256 * 4;
    int* idsA = (int*)(ws + off);        off += 256 * MAXLEN * 4;
    int* idsB = (int*)(ws + off);        off += 256 * MAXLEN * 4;
    float* candV = (float*)(ws + off);   off += 256 * 32 * 4;
    int* candI = (int*)(ws + off);       off += 256 * 32 * 4;

    if (ws_size < off) return;

    k_init<<<B, 256, 0, stream>>>(initial_ids, state, cacheA, idsA, scoresA);

    float* cCur = cacheA; float* cNxt = cacheB;
    float* sCur = scoresA; float* sNxt = scoresB;
    int* iCur = idsA; int* iNxt = idsB;

    for (int step = 0; step < STEPS; ++step) {
        int beam0 = (step == 0) ? 1 : BEAM;
        int rows = B * beam0;

        k_embed<<<rows, 256, 0, stream>>>(cCur, iCur, emb, U, x, step);

        dim3 gt(8, 8);
        k_trans<<<gt, 256, 0, stream>>>(x, xT);

        dim3 g((V + 255) / 256, (rows + 31) / 32);
        k_gemm<<<g, 256, 0, stream>>>(xT, W, L, rows);

        k_post<<<rows, 512, 0, stream>>>(L, sCur, candV, candI);
        k_merge<<<B, 256, 0, stream>>>(candV, candI, sNxt, iCur, iNxt, x, cNxt, beam0, step);

        float* tf; int* ti;
        tf = cCur; cCur = cNxt; cNxt = tf;
        tf = sCur; sCur = sNxt; sNxt = tf;
        ti = iCur; iCur = iNxt; iNxt = ti;
    }

    k_out<<<(B * BEAM * MAXLEN + B * BEAM + 255) / 256, 256, 0, stream>>>(iCur, sCur, (float*)d_out);
}

// Round 15
// 5115.622 us; speedup vs baseline: 31.3301x; 1.4853x over previous
//
// R15: parallel k_merge (32 extraction rounds in LDS; no FP arithmetic in merge).
// Everything else identical to the PASSING R14 kernel.
#include <hip/hip_runtime.h>
#include <math.h>

#define B 8
#define D 256
#define V 50257
#define VP 50304
#define BEAM 32
#define STEPS 16
#define MAXLEN 17
#define FNEG_INF (-3.4e38f)
#define NG 1571           // ceil(V/32)
#define NLCAP 800
#define SLOTCAP 1600

// ===== compile-time replica of numpy pairwise_sum recursion tree for n=V =====
struct SchedT {
    int nl, nops, nlev, root;
    int lvlStart[36];
    int leafOff[NLCAP];
    int leafN[NLCAP];
    int sA[NLCAP];
    int sB[NLCAP];
    int sD[NLCAP];
};

constexpr SchedT build_sched() {
    SchedT s{};
    int sOff[64] = {}, sN[64] = {}, sPh[64] = {};
    int vSlot[64] = {}, vLev[64] = {};
    int oA[NLCAP] = {}, oB[NLCAP] = {}, oD[NLCAP] = {}, oL[NLCAP] = {};
    int sp = 0, vp = 0, nl = 0, nops = 0;
    sOff[0] = 0; sN[0] = V; sPh[0] = 0; sp = 1;
    while (sp) {
        int i = sp - 1;
        int n = sN[i];
        if (n <= 128) {                        // leaf (np_pairwise base case)
            s.leafOff[nl] = sOff[i]; s.leafN[nl] = n;
            vSlot[vp] = nl; vLev[vp] = 0; ++vp; ++nl; --sp; continue;
        }
        int n2 = (n / 2) - ((n / 2) % 8);
        int ph = sPh[i];
        if (ph == 0)      { sPh[i] = 1; sOff[sp] = sOff[i];      sN[sp] = n2;     sPh[sp] = 0; ++sp; }
        else if (ph == 1) { sPh[i] = 2; sOff[sp] = sOff[i] + n2; sN[sp] = n - n2; sPh[sp] = 0; ++sp; }
        else {
            int bI = --vp; int aI = --vp;      // a = left child, b = right child
            int lev = (vLev[aI] > vLev[bI] ? vLev[aI] : vLev[bI]) + 1;
            oA[nops] = vSlot[aI]; oB[nops] = vSlot[bI]; oD[nops] = NLCAP + nops; oL[nops] = lev;
            vSlot[vp] = NLCAP + nops; vLev[vp] = lev; ++vp; ++nops; --sp;
        }
    }
    s.nl = nl; s.nops = nops; s.root = vSlot[0];
    int maxl = 0;
    for (int k = 0; k < nops; ++k) if (oL[k] > maxl) maxl = oL[k];
    s.nlev = maxl;
    int cnt[36] = {};
    for (int k = 0; k < nops; ++k) cnt[oL[k]]++;
    int run = 0;
    s.lvlStart[0] = 0;
    for (int k = 1; k <= maxl; ++k) { s.lvlStart[k] = run; run += cnt[k]; cnt[k] = s.lvlStart[k]; }
    s.lvlStart[maxl + 1] = run;
    for (int k = 0; k < nops; ++k) { int p = cnt[oL[k]]++; s.sA[p] = oA[k]; s.sB[p] = oB[k]; s.sD[p] = oD[k]; }
    return s;
}

constexpr SchedT SCH = build_sched();
static_assert(SCH.nl <= NLCAP, "leaf overflow");
static_assert(SCH.nops <= NLCAP, "op overflow");
static_assert(SCH.nlev <= 34, "level overflow");
static_assert(SCH.root < SLOTCAP, "slot overflow");

// -------- init --------
__global__ void k_init(const int* __restrict__ initial_ids, const float* __restrict__ state,
                       float* __restrict__ cache, int* __restrict__ ids, float* __restrict__ scores) {
    int b = blockIdx.x, t = threadIdx.x;
    cache[b * D + t] = state[b * D + t];
    if (t == 0) { ids[b * MAXLEN] = initial_ids[b]; scores[b] = 0.f; }
}

// -------- x = tanh(seqdot(cache,U) + emb[last]) on the f32 grid --------
__global__ __launch_bounds__(256) void k_embed(const float* __restrict__ cache, const int* __restrict__ ids,
                                               const float* __restrict__ emb, const float* __restrict__ U,
                                               float* __restrict__ x, int step) {
    int rr = blockIdx.x, j = threadIdx.x;
    __shared__ float sc[D];
    sc[j] = cache[rr * D + j];
    __syncthreads();
    int last = ids[rr * MAXLEN + step];
    float acc = 0.f;
    for (int d = 0; d < D; ++d)
        acc = __fadd_rn(acc, __fmul_rn(sc[d], U[d * D + j]));   // sequential f32, no FMA
    float pre = __fadd_rn(acc, emb[(size_t)last * D + j]);
    x[rr * D + j] = (float)tanh((double)pre);
}

// -------- 256x256 transpose: xT[c][r] = x[r][c] --------
__global__ __launch_bounds__(256) void k_trans(const float* __restrict__ x, float* __restrict__ xT) {
    __shared__ float tile[32][33];
    int t = threadIdx.x;
    int tx = t & 31, ty = t >> 5;          // 32 x 8
    int bx = blockIdx.x * 32, by = blockIdx.y * 32;
#pragma unroll
    for (int i = 0; i < 4; ++i)
        tile[ty + i * 8][tx] = x[(size_t)(by + ty + i * 8) * D + bx + tx];
    __syncthreads();
#pragma unroll
    for (int i = 0; i < 4; ++i)
        xT[(size_t)(bx + ty + i * 8) * 256 + by + tx] = tile[tx][ty + i * 8];
}

// -------- logits GEMM: LDS-free; x values wave-uniform (scalar loads) --------
__global__ __launch_bounds__(256) void k_gemm(const float* __restrict__ xT, const float* __restrict__ W,
                                              float* __restrict__ L, int rows) {
    int t = threadIdx.x;
    int v = blockIdx.x * 256 + t;
    int r0 = blockIdx.y * 32;
    if (v >= V) return;
    float acc[32];
#pragma unroll
    for (int r = 0; r < 32; ++r) acc[r] = 0.f;
    for (int d = 0; d < D; ++d) {
        float w = W[(size_t)d * V + v];                  // coalesced vector load
        const float* xp = xT + d * 256 + r0;             // block-uniform -> s_load
#pragma unroll
        for (int r = 0; r < 32; ++r)
            acc[r] = __fadd_rn(acc[r], __fmul_rn(xp[r], w));   // same per-(r,v) order as R10-R14
    }
#pragma unroll
    for (int r = 0; r < 32; ++r)
        if (r0 + r < rows) L[(size_t)(r0 + r) * VP + v] = acc[r];
}

// -------- exact numpy-pairwise base-case leaf sum with inlined exp --------
__device__ __forceinline__ float Ev(const float* __restrict__ a, float m, int i) {
    return (float)exp((double)__fsub_rn(a[i], m));
}
__device__ float leaf_sum(const float* __restrict__ a, int n, float m) {
    if (n < 8) {
        if (n <= 0) return 0.f;
        float r = Ev(a, m, 0);
        for (int i = 1; i < n; ++i) r = __fadd_rn(r, Ev(a, m, i));
        return r;
    }
    float r0 = Ev(a,m,0), r1 = Ev(a,m,1), r2 = Ev(a,m,2), r3 = Ev(a,m,3);
    float r4 = Ev(a,m,4), r5 = Ev(a,m,5), r6 = Ev(a,m,6), r7 = Ev(a,m,7);
    int i;
    for (i = 8; i < n - (n % 8); i += 8) {
        r0 = __fadd_rn(r0, Ev(a,m,i+0)); r1 = __fadd_rn(r1, Ev(a,m,i+1));
        r2 = __fadd_rn(r2, Ev(a,m,i+2)); r3 = __fadd_rn(r3, Ev(a,m,i+3));
        r4 = __fadd_rn(r4, Ev(a,m,i+4)); r5 = __fadd_rn(r5, Ev(a,m,i+5));
        r6 = __fadd_rn(r6, Ev(a,m,i+6)); r7 = __fadd_rn(r7, Ev(a,m,i+7));
    }
    float res = __fadd_rn(__fadd_rn(__fadd_rn(r0, r1), __fadd_rn(r2, r3)),
                          __fadd_rn(__fadd_rn(r4, r5), __fadd_rn(r6, r7)));
    for (; i < n; ++i) res = __fadd_rn(res, Ev(a,m,i));
    return res;
}

// -------- fused: max + lsf + per-row top-32 --------
__global__ __launch_bounds__(512) void k_post(const float* __restrict__ L, const float* __restrict__ scores,
                                              float* __restrict__ candV, int* __restrict__ candI) {
    int rr = blockIdx.x, t = threadIdx.x;
    const float* Lr = L + (size_t)rr * VP;
    __shared__ float red[512];
    __shared__ int ri[512];
    __shared__ float vals[SLOTCAP];
    __shared__ float gval[NG]; __shared__ int gidx[NG]; __shared__ unsigned gmask[NG];

    // ---- max (order-independent) ----
    float mx = FNEG_INF;
    const float4* L4 = (const float4*)Lr;
    for (int i = t; i < V / 4; i += 512) {
        float4 p = L4[i];
        mx = fmaxf(mx, fmaxf(fmaxf(p.x, p.y), fmaxf(p.z, p.w)));
    }
    if (t == 0) mx = fmaxf(mx, Lr[V - 1]);
    red[t] = mx; __syncthreads();
    for (int o = 256; o > 0; o >>= 1) { if (t < o) red[t] = fmaxf(red[t], red[t + o]); __syncthreads(); }
    float m = red[0];

    // ---- lsf: parallel leaf sums + level-parallel exact combine ----
    for (int l = t; l < SCH.nl; l += 512)
        vals[l] = leaf_sum(Lr + SCH.leafOff[l], SCH.leafN[l], m);
    __syncthreads();
    for (int lev = 1; lev <= SCH.nlev; ++lev) {
        for (int i = SCH.lvlStart[lev] + t; i < SCH.lvlStart[lev + 1]; i += 512)
            vals[SCH.sD[i]] = __fadd_rn(vals[SCH.sA[i]], vals[SCH.sB[i]]);
        __syncthreads();
    }
    float lsf = (float)log((double)vals[SCH.root]);
    float sc = scores[rr];

    // ---- group maxima over 32-token groups ----
    for (int g = t; g < NG; g += 512) {
        int c0 = g * 32;
        int lim = (V - c0) < 32 ? (V - c0) : 32;
        float bv = FNEG_INF; int bi = 0x7fffffff;
        for (int c = 0; c < lim; ++c) {
            int vtok = c0 + c;
            float val = __fadd_rn(sc, __fsub_rn(__fsub_rn(Lr[vtok], m), lsf));
            if (val > bv) { bv = val; bi = vtok; }       // ties keep lower idx
        }
        gval[g] = bv; gidx[g] = bi; gmask[g] = 0u;
    }
    __syncthreads();

    // ---- 32 extract rounds ----
    for (int it = 0; it < 32; ++it) {
        float bv = FNEG_INF; int bi = 0x7fffffff;
        for (int g = t; g < NG; g += 512) {
            float gv = gval[g]; int gi = gidx[g];
            if (gv > bv || (gv == bv && gi < bi)) { bv = gv; bi = gi; }
        }
        red[t] = bv; ri[t] = bi; __syncthreads();
        for (int o = 256; o > 0; o >>= 1) {
            if (t < o) {
                if (red[t + o] > red[t] || (red[t + o] == red[t] && ri[t + o] < ri[t])) { red[t] = red[t + o]; ri[t] = ri[t + o]; }
            }
            __syncthreads();
        }
        int wcol = ri[0]; int wg = wcol >> 5;
        if (t == 0) {
            candV[rr * 32 + it] = red[0];
            candI[rr * 32 + it] = wcol;
            gmask[wg] |= (1u << (wcol & 31));
        }
        __syncthreads();
        if (t < 32) {                                    // rescan winning group
            int col = wg * 32 + t;
            unsigned msk = gmask[wg];
            bool live = (col < V) && !((msk >> t) & 1u);
            float val = live ? __fadd_rn(sc, __fsub_rn(__fsub_rn(Lr[col], m), lsf)) : FNEG_INF;
            int ix = live ? col : 0x7fffffff;
            for (int o = 16; o > 0; o >>= 1) {
                float v2 = __shfl_down(val, o, 32);
                int i2 = __shfl_down(ix, o, 32);
                if (v2 > val || (v2 == val && i2 < ix)) { val = v2; ix = i2; }
            }
            if (t == 0) { gval[wg] = val; gidx[wg] = ix; }
        }
        __syncthreads();
    }
}

// -------- PARALLEL per-batch merge: LDS extraction rounds (no FP arithmetic) --------
__global__ __launch_bounds__(256) void k_merge(const float* __restrict__ candV, const int* __restrict__ candI,
                                               float* __restrict__ scoresNxt,
                                               const int* __restrict__ idsCur, int* __restrict__ idsNxt,
                                               const float* __restrict__ x, float* __restrict__ cacheNxt,
                                               int beam0, int step) {
    int b = blockIdx.x, t = threadIdx.x;
    int n = beam0 * BEAM;
    __shared__ float mval[BEAM * BEAM]; __shared__ int mbeam[BEAM * BEAM]; __shared__ int mtok[BEAM * BEAM];
    __shared__ float rv[256]; __shared__ int rk[256]; __shared__ int rs[256];
    __shared__ float wval[BEAM]; __shared__ int wbeam[BEAM]; __shared__ int wtok[BEAM];

    for (int i = t; i < n; i += 256) {
        int beam = i >> 5;
        int rr = b * beam0 + beam;
        mval[i] = candV[rr * BEAM + (i & 31)];
        mbeam[i] = beam;
        mtok[i] = candI[rr * BEAM + (i & 31)];
    }
    __syncthreads();

    for (int it = 0; it < BEAM; ++it) {
        float bv = FNEG_INF; int bk = 0x7fffffff; int bs = -1;
        for (int i = t; i < n; i += 256) {
            float v = mval[i];
            int gi = mbeam[i] * V + mtok[i];
            if (v > bv || (v == bv && gi < bk)) { bv = v; bk = gi; bs = i; }
        }
        rv[t] = bv; rk[t] = bk; rs[t] = bs; __syncthreads();
        for (int o = 128; o > 0; o >>= 1) {
            if (t < o) {
                if (rv[t + o] > rv[t] || (rv[t + o] == rv[t] && rk[t + o] < rk[t])) {
                    rv[t] = rv[t + o]; rk[t] = rk[t + o]; rs[t] = rs[t + o];
                }
            }
            __syncthreads();
        }
        if (t == 0) {
            int w = rs[0];
            wval[it] = rv[0]; wbeam[it] = mbeam[w]; wtok[it] = mtok[w];
            mval[w] = FNEG_INF;                      // consume winner
        }
        __syncthreads();
    }

    if (t < BEAM) {
        scoresNxt[b * BEAM + t] = wval[t];
        int src = b * beam0 + wbeam[t];
        for (int u = 0; u <= step; ++u)
            idsNxt[(b * BEAM + t) * MAXLEN + u] = idsCur[src * MAXLEN + u];
        idsNxt[(b * BEAM + t) * MAXLEN + step + 1] = wtok[t];
    }
    __syncthreads();
    for (int j = 0; j < BEAM; ++j) {
        int src = b * beam0 + wbeam[j];
        cacheNxt[(size_t)(b * BEAM + j) * D + t] = x[(size_t)src * D + t];
    }
}

// -------- output as float32 --------
__global__ void k_out(const int* __restrict__ ids, const float* __restrict__ scores, float* __restrict__ out) {
    int t = blockIdx.x * 256 + threadIdx.x;
    const int NI = B * BEAM * MAXLEN;
    if (t < NI) out[t] = (float)ids[t];
    else if (t < NI + B * BEAM) out[t] = scores[t - NI];
}

extern "C" void kernel_launch(void* const* d_in, const int* in_sizes, int n_in,
                              void* d_out, int out_size, void* d_ws, size_t ws_size,
                              hipStream_t stream) {
    const int* initial_ids = (const int*)d_in[0];
    const float* state = (const float*)d_in[1];
    const float* emb = (const float*)d_in[2];
    const float* W = (const float*)d_in[3];
    const float* U = (const float*)d_in[4];

    char* ws = (char*)d_ws;
    size_t off = 0;
    float* L = (float*)(ws + off);       off += (size_t)256 * VP * 4;
    float* x = (float*)(ws + off);       off += 256 * D * 4;
    float* xT = (float*)(ws + off);      off += 256 * D * 4;
    float* cacheA = (float*)(ws + off);  off += 256 * D * 4;
    float* cacheB = (float*)(ws + off);  off += 256 * D * 4;
    float* scoresA = (float*)(ws + off); off += 256 * 4;
    float* scoresB = (float*)(ws + off); off += 256 * 4;
    int* idsA = (int*)(ws + off);        off += 256 * MAXLEN * 4;
    int* idsB = (int*)(ws + off);        off += 256 * MAXLEN * 4;
    float* candV = (float*)(ws + off);   off += 256 * 32 * 4;
    int* candI = (int*)(ws + off);       off += 256 * 32 * 4;

    if (ws_size < off) return;

    k_init<<<B, 256, 0, stream>>>(initial_ids, state, cacheA, idsA, scoresA);

    float* cCur = cacheA; float* cNxt = cacheB;
    float* sCur = scoresA; float* sNxt = scoresB;
    int* iCur = idsA; int* iNxt = idsB;

    for (int step = 0; step < STEPS; ++step) {
        int beam0 = (step == 0) ? 1 : BEAM;
        int rows = B * beam0;

        k_embed<<<rows, 256, 0, stream>>>(cCur, iCur, emb, U, x, step);

        dim3 gt(8, 8);
        k_trans<<<gt, 256, 0, stream>>>(x, xT);

        dim3 g((V + 255) / 256, (rows + 31) / 32);
        k_gemm<<<g, 256, 0, stream>>>(xT, W, L, rows);

        k_post<<<rows, 512, 0, stream>>>(L, sCur, candV, candI);
        k_merge<<<B, 256, 0, stream>>>(candV, candI, sNxt, iCur, iNxt, x, cNxt, beam0, step);

        float* tf; int* ti;
        tf = cCur; cCur = cNxt; cNxt = tf;
        tf = sCur; sCur = sNxt; sNxt = tf;
        ti = iCur; iCur = iNxt; iNxt = ti;
    }

    k_out<<<(B * BEAM * MAXLEN + B * BEAM + 255) / 256, 256, 0, stream>>>(iCur, sCur, (float*)d_out);
}